// Round 8
// baseline (171.013 us; speedup 1.0000x reference)
//
#include <hip/hip_runtime.h>

// Problem constants (from reference): B=4096, N_ELEM=2048, N_NODES=1024, E2=4096
#define B_SAMPLES 4096
#define N_ELEM    2048
#define N_NODES   1024
#define E2        4096
#define MBLOCK    512                    // main kernel block
#define S         8                      // samples per main block
#define MAIN_BLOCKS (B_SAMPLES / S)      // 512

// Workspace layout (bytes):
//   [0, 8K)     : offs[N_NODES+1]  (int; exclusive scan of per-node counts)
//   [8K, +32K)  : csrw[E2]         (float2 {wx, wy}, grouped by node)
//   [40K, +16K) : csrid[E2]        (int swizzled eid, grouped by node)
//   [56K, +2K)  : partial[MAIN_BLOCKS] (float)
#define WS_OFFS_OFF   0
#define WS_CSRW_OFF   8192
#define WS_CSRID_OFF  (8192 + E2 * 8)
#define WS_PART_OFF   (WS_CSRID_OFF + E2 * 4)

// LDS element swizzle: elem (4c+j) lives at slot j*512 + c, so phase-1's
// per-thread writes of 4 consecutive elems become 4 stride-1 (16B/lane)
// conflict-free b128 stores. Gather pays nothing: build stores swizzled ids.
__host__ __device__ __forceinline__ int swz_eid(int eid) {
    return ((eid & 3) << 9) | (eid >> 2);
}

// ---------------------------------------------------------------------------
// Build: ONE single-block kernel producing exact CSR (no SLOTS truncation).
// count (LDS atomics) -> exclusive scan (wave shfl + block) -> cursor fill.
// Per-node slot order is atomic-nondeterministic — same class as the old ELL
// build, which has passed with absmax 0.0 on every run.
// ---------------------------------------------------------------------------
__global__ __launch_bounds__(1024) void neq_build_kernel(
    const float* __restrict__ vecs, const int* __restrict__ node_ids,
    const int* __restrict__ elem_ids,
    int* __restrict__ offs, float2* __restrict__ csrw, int* __restrict__ csrid)
{
    __shared__ int scnt[N_NODES];
    __shared__ int soff[N_NODES];
    __shared__ int wsum[16];
    const int t = threadIdx.x;                           // 0..1023
    const int lane = t & 63, wid = t >> 6;

    scnt[t] = 0;
    __syncthreads();
#pragma unroll
    for (int i = 0; i < 4; ++i)
        atomicAdd(&scnt[node_ids[t + i * 1024]], 1);
    __syncthreads();

    // exclusive scan of scnt[0..1023]
    int c = scnt[t];
    int v = c;                                           // inclusive within wave
#pragma unroll
    for (int off = 1; off < 64; off <<= 1) {
        int u = __shfl_up(v, off, 64);
        if (lane >= off) v += u;
    }
    if (lane == 63) wsum[wid] = v;
    __syncthreads();
    if (wid == 0) {
        int s = (lane < 16) ? wsum[lane] : 0;
#pragma unroll
        for (int off = 1; off < 16; off <<= 1) {
            int u = __shfl_up(s, off, 64);
            if (lane >= off) s += u;
        }
        if (lane < 16) wsum[lane] = s;
    }
    __syncthreads();
    int wbase = (wid == 0) ? 0 : wsum[wid - 1];
    int excl = wbase + v - c;
    soff[t] = excl;
    offs[t] = excl;
    if (t == 1023) offs[1024] = excl + c;                // == E2
    __syncthreads();

    // fill: reuse scnt as per-node cursor
    scnt[t] = 0;
    __syncthreads();
#pragma unroll
    for (int i = 0; i < 4; ++i) {
        int j = t + i * 1024;
        int nid = node_ids[j];
        int slot = atomicAdd(&scnt[nid], 1);
        int pos = soff[nid] + slot;
        csrw[pos] = ((const float2*)vecs)[j];
        csrid[pos] = swz_eid(elem_ids[j]);
    }
}

// FMA of a float4 (4 samples) by a scalar weight into a float4 accumulator.
#define FMA4(A, V, W) do { (A).x += (V).x * (W); (A).y += (V).y * (W); \
                           (A).z += (V).z * (W); (A).w += (V).w * (W); } while (0)

// ---------------------------------------------------------------------------
// Main: one block (512 threads) per S=8 samples; 512 blocks = 1 block/CU
// (114 KiB LDS). The ENTIRE gather working set lives in LDS: axial tables
// (A: samples 0-3, B: samples 4-7; swizzled, conflict-free b128 writes) AND
// the compact CSR (48 KB). Phase 2 has zero global memory operations — pure
// ds_read + FMA — so no vmcnt chain can bind it. All global traffic is
// coalesced streaming (EA,e,q,r 128 MB unique + 24 MB CSR broadcast).
// Branchless tail: over-read entries (k >= count) get weight 0 via select;
// index clamped to E2-1 keeps LDS reads in-bounds.
// ---------------------------------------------------------------------------
__global__ __launch_bounds__(MBLOCK, 2) void neq_main_kernel(
    const float* __restrict__ EA, const float* __restrict__ e,
    const float* __restrict__ q,  const float* __restrict__ r,
    const int* __restrict__ offs, const float2* __restrict__ csrw,
    const int* __restrict__ csrid, float* __restrict__ partial)
{
    __shared__ float4 axialA[N_ELEM];    // 32 KiB: samples 0-3, swizzled
    __shared__ float4 axialB[N_ELEM];    // 32 KiB: samples 4-7, swizzled
    __shared__ float2 wlds[E2];          // 32 KiB: CSR weights
    __shared__ int    ilds[E2];          // 16 KiB: CSR swizzled eids
    __shared__ float  red[MBLOCK / 64];  // 8

    const int b0 = blockIdx.x * S;
    const int t = threadIdx.x;

    // ---- stage CSR (coalesced, stride-1 conflict-free LDS writes) ----
#pragma unroll
    for (int i = 0; i < 8; ++i) {
        wlds[t + i * 512] = csrw[t + i * 512];
        ilds[t + i * 512] = csrid[t + i * 512];
    }

    // per-node CSR ranges (thread owns nodes t, t+512)
    int o0 = offs[t];
    int c0 = offs[t + 1] - o0;
    int o1 = offs[t + 512];
    int c1 = offs[t + 513] - o1;
    int kmax = max(c0, c1);

    // ---- phase 1: 16 independent 16B loads, products, swizzled writes ----
    const float4* EA4 = (const float4*)(EA + (size_t)b0 * N_ELEM);   // 512 f4/row
    const float4* e4  = (const float4*)(e  + (size_t)b0 * N_ELEM);
    {
        float4 ea0 = EA4[0 * 512 + t];
        float4 ea1 = EA4[1 * 512 + t];
        float4 ea2 = EA4[2 * 512 + t];
        float4 ea3 = EA4[3 * 512 + t];
        float4 me0 = e4 [0 * 512 + t];
        float4 me1 = e4 [1 * 512 + t];
        float4 me2 = e4 [2 * 512 + t];
        float4 me3 = e4 [3 * 512 + t];
        float4 p0, p1, p2, p3;           // p_s = product of sample s, elems 4t..4t+3
        p0.x = ea0.x * me0.x; p0.y = ea0.y * me0.y; p0.z = ea0.z * me0.z; p0.w = ea0.w * me0.w;
        p1.x = ea1.x * me1.x; p1.y = ea1.y * me1.y; p1.z = ea1.z * me1.z; p1.w = ea1.w * me1.w;
        p2.x = ea2.x * me2.x; p2.y = ea2.y * me2.y; p2.z = ea2.z * me2.z; p2.w = ea2.w * me2.w;
        p3.x = ea3.x * me3.x; p3.y = ea3.y * me3.y; p3.z = ea3.z * me3.z; p3.w = ea3.w * me3.w;
        axialA[t]        = make_float4(p0.x, p1.x, p2.x, p3.x);   // elem 4t+0
        axialA[512 + t]  = make_float4(p0.y, p1.y, p2.y, p3.y);   // elem 4t+1
        axialA[1024 + t] = make_float4(p0.z, p1.z, p2.z, p3.z);   // elem 4t+2
        axialA[1536 + t] = make_float4(p0.w, p1.w, p2.w, p3.w);   // elem 4t+3
    }
    {
        float4 fa0 = EA4[4 * 512 + t];
        float4 fa1 = EA4[5 * 512 + t];
        float4 fa2 = EA4[6 * 512 + t];
        float4 fa3 = EA4[7 * 512 + t];
        float4 fm0 = e4 [4 * 512 + t];
        float4 fm1 = e4 [5 * 512 + t];
        float4 fm2 = e4 [6 * 512 + t];
        float4 fm3 = e4 [7 * 512 + t];
        float4 p0, p1, p2, p3;
        p0.x = fa0.x * fm0.x; p0.y = fa0.y * fm0.y; p0.z = fa0.z * fm0.z; p0.w = fa0.w * fm0.w;
        p1.x = fa1.x * fm1.x; p1.y = fa1.y * fm1.y; p1.z = fa1.z * fm1.z; p1.w = fa1.w * fm1.w;
        p2.x = fa2.x * fm2.x; p2.y = fa2.y * fm2.y; p2.z = fa2.z * fm2.z; p2.w = fa2.w * fm2.w;
        p3.x = fa3.x * fm3.x; p3.y = fa3.y * fm3.y; p3.z = fa3.z * fm3.z; p3.w = fa3.w * fm3.w;
        axialB[t]        = make_float4(p0.x, p1.x, p2.x, p3.x);
        axialB[512 + t]  = make_float4(p0.y, p1.y, p2.y, p3.y);
        axialB[1024 + t] = make_float4(p0.z, p1.z, p2.z, p3.z);
        axialB[1536 + t] = make_float4(p0.w, p1.w, p2.w, p3.w);
    }
    __syncthreads();

    // ---- phase 2: gather — pure LDS, zero global ops ----
    float4 xA0 = make_float4(0.f, 0.f, 0.f, 0.f);   // node t,    x, samples 0-3
    float4 yA0 = make_float4(0.f, 0.f, 0.f, 0.f);
    float4 xB0 = make_float4(0.f, 0.f, 0.f, 0.f);   // node t,    x, samples 4-7
    float4 yB0 = make_float4(0.f, 0.f, 0.f, 0.f);
    float4 xA1 = make_float4(0.f, 0.f, 0.f, 0.f);   // node t+512
    float4 yA1 = make_float4(0.f, 0.f, 0.f, 0.f);
    float4 xB1 = make_float4(0.f, 0.f, 0.f, 0.f);
    float4 yB1 = make_float4(0.f, 0.f, 0.f, 0.f);

    for (int k = 0; k < kmax; ++k) {
        int i0 = min(o0 + k, E2 - 1);
        int i1 = min(o1 + k, E2 - 1);
        float2 w0 = wlds[i0];
        float2 w1 = wlds[i1];
        int id0 = ilds[i0];
        int id1 = ilds[i1];
        if (k >= c0) w0 = make_float2(0.f, 0.f);     // branchless tail
        if (k >= c1) w1 = make_float2(0.f, 0.f);
        float4 A0 = axialA[id0];
        float4 B0 = axialB[id0];
        float4 A1 = axialA[id1];
        float4 B1 = axialB[id1];
        FMA4(xA0, A0, w0.x);  FMA4(yA0, A0, w0.y);
        FMA4(xB0, B0, w0.x);  FMA4(yB0, B0, w0.y);
        FMA4(xA1, A1, w1.x);  FMA4(yA1, A1, w1.y);
        FMA4(xB1, B1, w1.x);  FMA4(yB1, B1, w1.y);
    }

    // ---- phase 3: residual & sum of squares (per sample; q/r loaded late) ----
    float acc = 0.f;
#pragma unroll
    for (int s = 0; s < 4; ++s) {                        // samples 0-3 (A set)
        const float2* q2 = (const float2*)(q + (size_t)(b0 + s) * N_NODES * 2);
        const float2* r2 = (const float2*)(r + (size_t)(b0 + s) * N_NODES * 2);
        float2 qa = q2[t],       ra = r2[t];
        float2 qb = q2[t + 512], rb = r2[t + 512];
        float ax0 = (s == 0) ? xA0.x : (s == 1) ? xA0.y : (s == 2) ? xA0.z : xA0.w;
        float ay0 = (s == 0) ? yA0.x : (s == 1) ? yA0.y : (s == 2) ? yA0.z : yA0.w;
        float ax1 = (s == 0) ? xA1.x : (s == 1) ? xA1.y : (s == 2) ? xA1.z : xA1.w;
        float ay1 = (s == 0) ? yA1.x : (s == 1) ? yA1.y : (s == 2) ? yA1.z : yA1.w;
        float x = ax0 - qa.x - ra.x;
        float y = ay0 - qa.y - ra.y;
        acc += x * x + y * y;
        x = ax1 - qb.x - rb.x;
        y = ay1 - qb.y - rb.y;
        acc += x * x + y * y;
    }
#pragma unroll
    for (int s = 0; s < 4; ++s) {                        // samples 4-7 (B set)
        const float2* q2 = (const float2*)(q + (size_t)(b0 + 4 + s) * N_NODES * 2);
        const float2* r2 = (const float2*)(r + (size_t)(b0 + 4 + s) * N_NODES * 2);
        float2 qa = q2[t],       ra = r2[t];
        float2 qb = q2[t + 512], rb = r2[t + 512];
        float ax0 = (s == 0) ? xB0.x : (s == 1) ? xB0.y : (s == 2) ? xB0.z : xB0.w;
        float ay0 = (s == 0) ? yB0.x : (s == 1) ? yB0.y : (s == 2) ? yB0.z : yB0.w;
        float ax1 = (s == 0) ? xB1.x : (s == 1) ? xB1.y : (s == 2) ? xB1.z : xB1.w;
        float ay1 = (s == 0) ? yB1.x : (s == 1) ? yB1.y : (s == 2) ? yB1.z : yB1.w;
        float x = ax0 - qa.x - ra.x;
        float y = ay0 - qa.y - ra.y;
        acc += x * x + y * y;
        x = ax1 - qb.x - rb.x;
        y = ay1 - qb.y - rb.y;
        acc += x * x + y * y;
    }

    // ---- wave + block reduce (8 waves) ----
#pragma unroll
    for (int off = 32; off > 0; off >>= 1)
        acc += __shfl_down(acc, off, 64);
    if ((t & 63) == 0) red[t >> 6] = acc;
    __syncthreads();
    if (t == 0) {
        float s = 0.f;
#pragma unroll
        for (int w = 0; w < MBLOCK / 64; ++w) s += red[w];
        partial[blockIdx.x] = s;
    }
}

// Reduce the per-block partials and apply the mean scale.
__global__ __launch_bounds__(512) void neq_reduce_kernel(
    const float* __restrict__ partial, float* __restrict__ out)
{
    __shared__ float red[512 / 64];
    const int t = threadIdx.x;
    float acc = partial[t];                              // MAIN_BLOCKS == 512
#pragma unroll
    for (int off = 32; off > 0; off >>= 1)
        acc += __shfl_down(acc, off, 64);
    if ((t & 63) == 0) red[t >> 6] = acc;
    __syncthreads();
    if (t == 0) {
        float s = 0.f;
#pragma unroll
        for (int w = 0; w < 512 / 64; ++w) s += red[w];
        const float inv_n = 1.0f / (float)((size_t)B_SAMPLES * N_NODES * 2);
        out[0] = s * inv_n;
    }
}

extern "C" void kernel_launch(void* const* d_in, const int* in_sizes, int n_in,
                              void* d_out, int out_size, void* d_ws, size_t ws_size,
                              hipStream_t stream) {
    const float* EA       = (const float*)d_in[0];
    const float* e        = (const float*)d_in[1];
    const float* q        = (const float*)d_in[2];
    const float* r        = (const float*)d_in[3];
    const float* vecs     = (const float*)d_in[4];
    const int*   node_ids = (const int*)d_in[5];
    const int*   elem_ids = (const int*)d_in[6];

    char* ws = (char*)d_ws;
    int*    offs    = (int*)(ws + WS_OFFS_OFF);
    float2* csrw    = (float2*)(ws + WS_CSRW_OFF);
    int*    csrid   = (int*)(ws + WS_CSRID_OFF);
    float*  partial = (float*)(ws + WS_PART_OFF);

    neq_build_kernel<<<1, 1024, 0, stream>>>(
        vecs, node_ids, elem_ids, offs, csrw, csrid);
    neq_main_kernel<<<MAIN_BLOCKS, MBLOCK, 0, stream>>>(
        EA, e, q, r, offs, csrw, csrid, partial);
    neq_reduce_kernel<<<1, 512, 0, stream>>>(partial, (float*)d_out);
}